// Round 10
// baseline (16711.386 us; speedup 1.0000x reference)
//
#include <hip/hip_runtime.h>

typedef __attribute__((ext_vector_type(8))) short short8;
typedef __attribute__((ext_vector_type(4))) float f32x4;
typedef __attribute__((ext_vector_type(2))) unsigned long long u64x2;
typedef unsigned short u16;
typedef unsigned int u32;
typedef unsigned long long u64;

// ---------------- workspace layout (bytes) ----------------
// xb:  [512][64 b][512 i] bf16                          = 33,554,432
// h0h: [513][128 chunk][64 b][8 u] bf16 (slot t+1=h[t]) = 67,239,936
// h1h: same                                             = 67,239,936
// No flags. Unwritten h dword = 0xFFFFFFFF (bf16 NaN pair) sentinel.
#define XB_OFF 0ul
#define H0_OFF 33554432ul
#define H1_OFF 100794368ul
#define HLEN   134479872ul

// ---------------- LDS layout (bytes) ----------------
#define WB_MAX    131072                  // 32 cols * 2*K bytes (K=2048 for L1)
#define GATES_OFF WB_MAX                  // [64][33] f32 = 8448
#define CST_OFF   (WB_MAX + 8448)         // [64][8]  f32 = 2048
#define BIAS_OFF  (WB_MAX + 8448 + 2048)  // [32] f32 = 128
#define LDS_TOTAL (WB_MAX + 8448 + 2048 + 128)   // 141696 <= 163840

#define SENT 0xFFFFFFFFFFFFFFFFull

__device__ __forceinline__ u16 f2bf(float f) {
  u32 u = __float_as_uint(f);
  return (u16)((u + 0x7fffu + ((u >> 16) & 1u)) >> 16);   // RNE
}
__device__ __forceinline__ float bf2f(u16 s) { return __uint_as_float(((u32)s) << 16); }

// compiler-managed agent-scope (IC) load/store: correct waitcnt + spill handling
__device__ __forceinline__ u64 ld_ic(const void* p) {
  return __hip_atomic_load((const u64*)p, __ATOMIC_RELAXED, __HIP_MEMORY_SCOPE_AGENT);
}
__device__ __forceinline__ void st_ic(u32* p, u32 v) {
  __hip_atomic_store(p, v, __ATOMIC_RELAXED, __HIP_MEMORY_SCOPE_AGENT);
}
__device__ __forceinline__ short8 mk8(u64 a, u64 b) {
  u64x2 t; t.x = a; t.y = b;
  return __builtin_bit_cast(short8, t);
}

// x[b][t][i] fp32 -> xb[t][b][i] bf16
__global__ __launch_bounds__(256) void prep_x(const float* __restrict__ x,
                                              u16* __restrict__ xb) {
  u32 stride = gridDim.x * blockDim.x;
  for (u32 e = blockIdx.x * blockDim.x + threadIdx.x; e < 16777216u; e += stride) {
    u32 i = e & 511u, b = (e >> 9) & 63u, t = e >> 15;
    xb[e] = f2bf(x[((size_t)b << 18) + ((size_t)t << 9) + i]);
  }
}

// Persistent kernel, 256 blocks (1/CU). Blocks 0..127: layer0 (K=1536=[x|h0prev]).
// Blocks 128..255: layer1 (K=2048=[h0cur|h1prev]).
// Sync protocol: data IS the flag. h history pre-set to NaN sentinel; consumers
// load fragments with agent-scope atomics and retry until sentinel-free.
// Producers store their 1KB chunk (agent atomics) and move on — no drain, no flag.
__global__ __launch_bounds__(256, 1) void lstm_persist(
    const u16* __restrict__ xb,
    const float* __restrict__ wih0, const float* __restrict__ whh0,
    const float* __restrict__ bih0, const float* __restrict__ bhh0,
    const float* __restrict__ wih1, const float* __restrict__ whh1,
    const float* __restrict__ bih1, const float* __restrict__ bhh1,
    u16* __restrict__ h0h, u16* __restrict__ h1h,
    const float* __restrict__ fc_w, const float* __restrict__ fc_b,
    float* __restrict__ out) {
  extern __shared__ char smem[];
  float* gates = (float*)(smem + GATES_OFF);  // [64][33]
  float* cst   = (float*)(smem + CST_OFF);    // [64][8]
  float* bias  = (float*)(smem + BIAS_OFF);   // [32]

  const int cu = blockIdx.x;
  const int layer = cu >> 7;
  const int lcu = cu & 127;
  const int U0 = lcu * 8;
  const int K2 = layer ? 4096 : 3072;         // bytes per LDS weight column
  const int tid = threadIdx.x;

  // ---- startup: pack weight columns; swizzle (n&7)<<4 -> 16B bank-slot spread
  for (int n = 0; n < 32; ++n) {
    const int grow = (n >> 3) * 1024 + U0 + (n & 7);
    char* colbase = smem + n * K2;
    const u32 swn = (u32)(n & 7) << 4;
    if (!layer) {
      const float* rih = wih0 + (size_t)grow * 512;
      const float* rhh = whh0 + (size_t)grow * 1024;
      for (int k = tid; k < 1536; k += 256) {
        float v = (k < 512) ? rih[k] : rhh[k - 512];
        *(u16*)(colbase + (((u32)k * 2u) ^ swn)) = f2bf(v);
      }
    } else {
      const float* rih = wih1 + (size_t)grow * 1024;
      const float* rhh = whh1 + (size_t)grow * 1024;
      for (int k = tid; k < 2048; k += 256) {
        float v = (k < 1024) ? rih[k] : rhh[k - 1024];
        *(u16*)(colbase + (((u32)k * 2u) ^ swn)) = f2bf(v);
      }
    }
  }
  if (tid < 32) {
    int grow = (tid >> 3) * 1024 + U0 + (tid & 7);
    bias[tid] = layer ? (bih1[grow] + bhh1[grow]) : (bih0[grow] + bhh0[grow]);
  }
  for (int i = tid; i < 512; i += 256) cst[i] = 0.0f;
  for (int i = tid; i < 2112; i += 256) gates[i] = 0.0f;
  __syncthreads();

  const int lane = tid & 63;
  const int wave = tid >> 6;
  const int lr = lane & 15;
  const int lq = lane >> 4;
  const int lkel = lq * 8;
  const u32 swz = (u32)(lr & 7) << 4;
  const char* wrow0 = smem + (size_t)lr * K2;
  const char* wrow1 = smem + (size_t)(16 + lr) * K2;

  // shared epilogue pieces -------------------------------------------------
  auto reduce_nonlin_store = [&](f32x4 acc[4][2], int t, u16* hist) {
    __syncthreads();   // bar1: prev step's gate reads/rezeros done in all waves
    #pragma unroll
    for (int mt = 0; mt < 4; ++mt)
      #pragma unroll
      for (int nt = 0; nt < 2; ++nt)
        #pragma unroll
        for (int r = 0; r < 4; ++r)
          atomicAdd(&gates[(mt * 16 + lq * 4 + r) * 33 + nt * 16 + lr],
                    acc[mt][nt][r]);
    __syncthreads();   // bar2: all contributions in

    const int b = tid >> 2;
    const int ub = (tid & 3) * 2;
    float hv[2];
    #pragma unroll
    for (int du = 0; du < 2; ++du) {
      const int u = ub + du;
      float gi = gates[b * 33 + u];       gates[b * 33 + u] = 0.0f;
      float gf = gates[b * 33 + 8 + u];   gates[b * 33 + 8 + u] = 0.0f;
      float gg = gates[b * 33 + 16 + u];  gates[b * 33 + 16 + u] = 0.0f;
      float go = gates[b * 33 + 24 + u];  gates[b * 33 + 24 + u] = 0.0f;
      gi += bias[u]; gf += bias[8 + u]; gg += bias[16 + u]; go += bias[24 + u];
      float ii = 1.0f / (1.0f + __expf(-gi));
      float ff = 1.0f / (1.0f + __expf(-gf));
      float g2 = 1.0f - 2.0f / (__expf(2.0f * gg) + 1.0f);
      float oo = 1.0f / (1.0f + __expf(-go));
      float c = ff * cst[b * 8 + u] + ii * g2;
      cst[b * 8 + u] = c;
      hv[du] = oo * (1.0f - 2.0f / (__expf(2.0f * c) + 1.0f));
    }
    u32 packed = (u32)f2bf(hv[0]) | ((u32)f2bf(hv[1]) << 16);
    u32* dst = (u32*)(hist + (size_t)(t + 1) * 65536 + ((size_t)lcu << 9)) + tid;
    st_ic(dst, packed);          // fire-and-forget: data IS the flag
  };

  if (!layer) {
    // ================= layer 0: K = [x(512) | h0prev(1024)] =================
    for (int t = 0; t < 512; ++t) {
      f32x4 z = {0.f, 0.f, 0.f, 0.f};
      f32x4 acc[4][2];
      #pragma unroll
      for (int a = 0; a < 4; ++a) { acc[a][0] = z; acc[a][1] = z; }

      auto mfma_tile = [&](short8 f0, short8 f1, short8 f2, short8 f3, int k0) {
        const u32 kb = ((u32)(k0 + lkel) * 2u) ^ swz;
        short8 b0 = *(const short8*)(wrow0 + kb);
        short8 b1 = *(const short8*)(wrow1 + kb);
        acc[0][0] = __builtin_amdgcn_mfma_f32_16x16x32_bf16(f0, b0, acc[0][0], 0, 0, 0);
        acc[1][0] = __builtin_amdgcn_mfma_f32_16x16x32_bf16(f1, b0, acc[1][0], 0, 0, 0);
        acc[2][0] = __builtin_amdgcn_mfma_f32_16x16x32_bf16(f2, b0, acc[2][0], 0, 0, 0);
        acc[3][0] = __builtin_amdgcn_mfma_f32_16x16x32_bf16(f3, b0, acc[3][0], 0, 0, 0);
        acc[0][1] = __builtin_amdgcn_mfma_f32_16x16x32_bf16(f0, b1, acc[0][1], 0, 0, 0);
        acc[1][1] = __builtin_amdgcn_mfma_f32_16x16x32_bf16(f1, b1, acc[1][1], 0, 0, 0);
        acc[2][1] = __builtin_amdgcn_mfma_f32_16x16x32_bf16(f2, b1, acc[2][1], 0, 0, 0);
        acc[3][1] = __builtin_amdgcn_mfma_f32_16x16x32_bf16(f3, b1, acc[3][1], 0, 0, 0);
      };

      short8 X[4][4];
      u64 H[8][4][2];
      const u16* Ax = xb + (size_t)t * 32768;
      #pragma unroll
      for (int j = 0; j < 4; ++j) {               // x part: plain cached loads
        const u16* ap = Ax + (size_t)lr * 512 + (wave + 4 * j) * 32 + lkel;
        X[j][0] = *(const short8*)(ap);
        X[j][1] = *(const short8*)(ap + 16 * 512);
        X[j][2] = *(const short8*)(ap + 32 * 512);
        X[j][3] = *(const short8*)(ap + 48 * 512);
      }
      if (t > 0) {
        const u16* Hs = h0h + (size_t)t * 65536 + (size_t)lr * 8;   // h0[t-1]
        auto issueH = [&] {
          #pragma unroll
          for (int j = 0; j < 8; ++j) {
            const u16* ap = Hs + ((size_t)(4 * wave + 16 * j + lq) << 9);
            #pragma unroll
            for (int q = 0; q < 4; ++q) {
              H[j][q][0] = ld_ic(ap + q * 128);
              H[j][q][1] = ld_ic(ap + q * 128 + 4);
            }
          }
        };
        issueH();
        // x-MFMA overlaps the h flight
        #pragma unroll
        for (int j = 0; j < 4; ++j)
          mfma_tile(X[j][0], X[j][1], X[j][2], X[j][3], (wave + 4 * j) * 32);
        for (;;) {
          u64 bad = 0;
          #pragma unroll
          for (int j = 0; j < 8; ++j)
            #pragma unroll
            for (int q = 0; q < 4; ++q)
              bad |= (u64)(H[j][q][0] == SENT) | (u64)(H[j][q][1] == SENT);
          if (!__any((int)(bad != 0))) break;
          __builtin_amdgcn_s_sleep(2);
          issueH();
        }
        #pragma unroll
        for (int j = 0; j < 8; ++j)
          mfma_tile(mk8(H[j][0][0], H[j][0][1]), mk8(H[j][1][0], H[j][1][1]),
                    mk8(H[j][2][0], H[j][2][1]), mk8(H[j][3][0], H[j][3][1]),
                    512 + (wave + 4 * j) * 32);
      } else {
        #pragma unroll
        for (int j = 0; j < 4; ++j)
          mfma_tile(X[j][0], X[j][1], X[j][2], X[j][3], (wave + 4 * j) * 32);
      }

      reduce_nonlin_store(acc, t, h0h);
    }
  } else {
    // ============== layer 1: K = [h0cur(1024) | h1prev(1024)] ==============
    for (int t = 0; t < 512; ++t) {
      f32x4 z = {0.f, 0.f, 0.f, 0.f};
      f32x4 acc[4][2];
      #pragma unroll
      for (int a = 0; a < 4; ++a) { acc[a][0] = z; acc[a][1] = z; }

      auto mfma_tile = [&](short8 f0, short8 f1, short8 f2, short8 f3, int k0) {
        const u32 kb = ((u32)(k0 + lkel) * 2u) ^ swz;
        short8 b0 = *(const short8*)(wrow0 + kb);
        short8 b1 = *(const short8*)(wrow1 + kb);
        acc[0][0] = __builtin_amdgcn_mfma_f32_16x16x32_bf16(f0, b0, acc[0][0], 0, 0, 0);
        acc[1][0] = __builtin_amdgcn_mfma_f32_16x16x32_bf16(f1, b0, acc[1][0], 0, 0, 0);
        acc[2][0] = __builtin_amdgcn_mfma_f32_16x16x32_bf16(f2, b0, acc[2][0], 0, 0, 0);
        acc[3][0] = __builtin_amdgcn_mfma_f32_16x16x32_bf16(f3, b0, acc[3][0], 0, 0, 0);
        acc[0][1] = __builtin_amdgcn_mfma_f32_16x16x32_bf16(f0, b1, acc[0][1], 0, 0, 0);
        acc[1][1] = __builtin_amdgcn_mfma_f32_16x16x32_bf16(f1, b1, acc[1][1], 0, 0, 0);
        acc[2][1] = __builtin_amdgcn_mfma_f32_16x16x32_bf16(f2, b1, acc[2][1], 0, 0, 0);
        acc[3][1] = __builtin_amdgcn_mfma_f32_16x16x32_bf16(f3, b1, acc[3][1], 0, 0, 0);
      };

      u64 A[8][4][2], B[8][4][2];
      const u16* H0s = h0h + (size_t)(t + 1) * 65536 + (size_t)lr * 8;  // h0[t]
      const u16* H1s = h1h + (size_t)t * 65536 + (size_t)lr * 8;        // h1[t-1]
      auto issueAll = [&] {
        #pragma unroll
        for (int j = 0; j < 8; ++j) {
          const u16* ap = H0s + ((size_t)(4 * wave + 16 * j + lq) << 9);
          #pragma unroll
          for (int q = 0; q < 4; ++q) {
            A[j][q][0] = ld_ic(ap + q * 128);
            A[j][q][1] = ld_ic(ap + q * 128 + 4);
          }
        }
        if (t > 0) {
          #pragma unroll
          for (int j = 0; j < 8; ++j) {
            const u16* ap = H1s + ((size_t)(4 * wave + 16 * j + lq) << 9);
            #pragma unroll
            for (int q = 0; q < 4; ++q) {
              B[j][q][0] = ld_ic(ap + q * 128);
              B[j][q][1] = ld_ic(ap + q * 128 + 4);
            }
          }
        }
      };
      issueAll();
      for (;;) {
        u64 bad = 0;
        #pragma unroll
        for (int j = 0; j < 8; ++j)
          #pragma unroll
          for (int q = 0; q < 4; ++q)
            bad |= (u64)(A[j][q][0] == SENT) | (u64)(A[j][q][1] == SENT);
        if (t > 0) {
          #pragma unroll
          for (int j = 0; j < 8; ++j)
            #pragma unroll
            for (int q = 0; q < 4; ++q)
              bad |= (u64)(B[j][q][0] == SENT) | (u64)(B[j][q][1] == SENT);
        }
        if (!__any((int)(bad != 0))) break;
        __builtin_amdgcn_s_sleep(2);
        issueAll();
      }
      #pragma unroll
      for (int j = 0; j < 8; ++j)
        mfma_tile(mk8(A[j][0][0], A[j][0][1]), mk8(A[j][1][0], A[j][1][1]),
                  mk8(A[j][2][0], A[j][2][1]), mk8(A[j][3][0], A[j][3][1]),
                  (wave + 4 * j) * 32);
      if (t > 0) {
        #pragma unroll
        for (int j = 0; j < 8; ++j)
          mfma_tile(mk8(B[j][0][0], B[j][0][1]), mk8(B[j][1][0], B[j][1][1]),
                    mk8(B[j][2][0], B[j][2][1]), mk8(B[j][3][0], B[j][3][1]),
                    1024 + (wave + 4 * j) * 32);
      }

      reduce_nonlin_store(acc, t, h1h);
    }
  }

  // ---- FC + softmax epilogue on block 0: sentinel-retry stage h1[511] -> LDS
  if (cu == 0) {
    __syncthreads();
    u16* smem16 = (u16*)smem;                       // weight area, now dead
    const u64* src = (const u64*)(h1h + (size_t)512 * 65536) + (size_t)tid * 64;
    u64 S[64];
    auto issueS = [&] {
      #pragma unroll
      for (int k = 0; k < 64; ++k) S[k] = ld_ic(src + k);
    };
    issueS();
    for (;;) {
      u64 bad = 0;
      #pragma unroll
      for (int k = 0; k < 64; ++k) bad |= (u64)(S[k] == SENT);
      if (!__any((int)(bad != 0))) break;
      __builtin_amdgcn_s_sleep(2);
      issueS();
    }
    u64* dls = (u64*)smem16 + (size_t)tid * 64;
    #pragma unroll
    for (int k = 0; k < 64; ++k) dls[k] = S[k];
    __syncthreads();
    if (tid < 128) {
      const int b = tid >> 1, cls = tid & 1;
      const float* w = fc_w + (size_t)cls * 1024;
      float sum = fc_b[cls];
      for (int c = 0; c < 128; ++c) {
        #pragma unroll
        for (int e = 0; e < 8; ++e)
          sum += bf2f(smem16[c * 512 + b * 8 + e]) * w[c * 8 + e];
      }
      float other = __shfl_xor(sum, 1);
      float mx = fmaxf(sum, other);
      float e0 = __expf(sum - mx), e1 = __expf(other - mx);
      out[b * 2 + cls] = e0 / (e0 + e1);
    }
  }
}

extern "C" void kernel_launch(void* const* d_in, const int* in_sizes, int n_in,
                              void* d_out, int out_size, void* d_ws, size_t ws_size,
                              hipStream_t stream) {
  const float* x    = (const float*)d_in[0];
  const float* wih0 = (const float*)d_in[1];
  const float* whh0 = (const float*)d_in[2];
  const float* bih0 = (const float*)d_in[3];
  const float* bhh0 = (const float*)d_in[4];
  const float* wih1 = (const float*)d_in[5];
  const float* whh1 = (const float*)d_in[6];
  const float* bih1 = (const float*)d_in[7];
  const float* bhh1 = (const float*)d_in[8];
  const float* fcw  = (const float*)d_in[9];
  const float* fcb  = (const float*)d_in[10];
  float* out = (float*)d_out;
  char* ws = (char*)d_ws;

  u16* xb  = (u16*)(ws + XB_OFF);
  u16* h0h = (u16*)(ws + H0_OFF);
  u16* h1h = (u16*)(ws + H1_OFF);

  (void)hipFuncSetAttribute((const void*)lstm_persist,
      hipFuncAttributeMaxDynamicSharedMemorySize, LDS_TOTAL);

  // h history -> 0xFF (bf16 NaN) sentinel: unwritten == not-yet-published
  hipMemsetAsync(ws + H0_OFF, 0xFF, HLEN, stream);
  prep_x<<<8192, 256, 0, stream>>>(x, xb);
  lstm_persist<<<256, 256, LDS_TOTAL, stream>>>(
      (const u16*)xb, wih0, whh0, bih0, bhh0, wih1, whh1, bih1, bhh1,
      h0h, h1h, fcw, fcb, out);
}

// Round 11
// 3727.356 us; speedup vs baseline: 4.4834x; 4.4834x over previous
//
#include <hip/hip_runtime.h>

typedef __attribute__((ext_vector_type(8))) short short8;
typedef __attribute__((ext_vector_type(4))) float f32x4;
typedef __attribute__((ext_vector_type(2))) unsigned int u32x2;
typedef unsigned short u16;
typedef unsigned int u32;

// ---------------- workspace layout (bytes) ----------------
// xb:  [512][64 b][512 i] bf16                              = 33,554,432
// h0h: [513][4 g][128 chunk][16 b][8 u] bf16 (slot t+1=h[t])= 67,239,936
// h1h: same                                                 = 67,239,936
// flags: [2 layer][4 group][128 chunk] monotonic, 32B stride = 32,768
#define XB_OFF 0ul
#define H0_OFF 33554432ul
#define H1_OFF 100794368ul
#define FL_OFF 168034304ul
#define FLAGS_LEN 32768ul

#define LDS_TOTAL 131072   // weights only: 32 cols * K2 (K2=4096B for layer1)

__device__ __forceinline__ u16 f2bf(float f) {
  u32 u = __float_as_uint(f);
  return (u16)((u + 0x7fffu + ((u >> 16) & 1u)) >> 16);   // RNE
}
__device__ __forceinline__ float bf2f(u16 s) { return __uint_as_float(((u32)s) << 16); }

// x[b][t][i] fp32 -> xb[t][b][i] bf16
__global__ __launch_bounds__(256) void prep_x(const float* __restrict__ x,
                                              u16* __restrict__ xb) {
  u32 stride = gridDim.x * blockDim.x;
  for (u32 e = blockIdx.x * blockDim.x + threadIdx.x; e < 16777216u; e += stride) {
    u32 i = e & 511u, b = (e >> 9) & 63u, t = e >> 15;
    xb[e] = f2bf(x[((size_t)b << 18) + ((size_t)t << 9) + i]);
  }
}

// Persistent kernel, 256 blocks (1/CU), 256 threads (4 waves).
// Blocks 0..127: layer0 (K=1536=[x|h0prev]); 128..255: layer1 (K=2048=[h0|h1prev]).
// Wave w = batch group w (16 batches). mfma(A=W, B=h): C=[gate-col x batch] ->
// cell update is wave-local after one shfl_xor(32). NO barriers in the main loop;
// each wave is an autonomous chain: poll -> load -> mfma -> nonlin -> store -> flag.
// Flags sc0sc1 (coherence point); h data loads plain-cached (fresh address per t:
// L2 miss pulls the fresh line once per XCD, then multicasts).
__global__ __launch_bounds__(256, 1) void lstm_persist(
    const u16* __restrict__ xb,
    const float* __restrict__ wih0, const float* __restrict__ whh0,
    const float* __restrict__ bih0, const float* __restrict__ bhh0,
    const float* __restrict__ wih1, const float* __restrict__ whh1,
    const float* __restrict__ bih1, const float* __restrict__ bhh1,
    u16* __restrict__ h0h, u16* __restrict__ h1h,
    u32* __restrict__ flags,
    const float* __restrict__ fc_w, const float* __restrict__ fc_b,
    float* __restrict__ out) {
  extern __shared__ char smem[];
  const int cu = blockIdx.x;
  const int layer = cu >> 7;
  const int lcu = cu & 127;
  const int U0 = lcu * 8;
  const int K2 = layer ? 4096 : 3072;         // bytes per LDS weight column
  const int tid = threadIdx.x;

  // ---- startup: pack 32 weight cols (col-major k, byte ^ (n&7)<<4) ----
  for (int n = 0; n < 32; ++n) {
    const int grow = (n >> 3) * 1024 + U0 + (n & 7);
    char* colbase = smem + n * K2;
    const u32 swn = (u32)(n & 7) << 4;
    if (!layer) {
      const float* rih = wih0 + (size_t)grow * 512;
      const float* rhh = whh0 + (size_t)grow * 1024;
      for (int k = tid; k < 1536; k += 256) {
        float v = (k < 512) ? rih[k] : rhh[k - 512];
        *(u16*)(colbase + (((u32)k * 2u) ^ swn)) = f2bf(v);
      }
    } else {
      const float* rih = wih1 + (size_t)grow * 1024;
      const float* rhh = whh1 + (size_t)grow * 1024;
      for (int k = tid; k < 2048; k += 256) {
        float v = (k < 1024) ? rih[k] : rhh[k - 1024];
        *(u16*)(colbase + (((u32)k * 2u) ^ swn)) = f2bf(v);
      }
    }
  }
  __syncthreads();   // last barrier before the main loop

  const int g = tid >> 6;            // wave = batch group (16 batches)
  const int lane = tid & 63;
  const int lr = lane & 15;          // batch row within group / col within tile
  const int lq = lane >> 4;
  const u32 swz = (u32)(lr & 7) << 4;
  const char* wrow0 = smem + (size_t)lr * K2;         // cols 0-15 (i|f units)
  const char* wrow1 = smem + (size_t)(16 + lr) * K2;  // cols 16-31 (g|o units)

  // per-lane bias regs: unit u = 4*(lq&1) + r
  float bi[4], bf_[4], bg[4], bo[4];
  {
    const float* s1 = layer ? bih1 : bih0;
    const float* s2 = layer ? bhh1 : bhh0;
    const int ug = U0 + 4 * (lq & 1);
    #pragma unroll
    for (int r = 0; r < 4; ++r) {
      bi[r]  = s1[ug + r]        + s2[ug + r];
      bf_[r] = s1[1024 + ug + r] + s2[1024 + ug + r];
      bg[r]  = s1[2048 + ug + r] + s2[2048 + ug + r];
      bo[r]  = s1[3072 + ug + r] + s2[3072 + ug + r];
    }
  }
  float cs[4] = {0.f, 0.f, 0.f, 0.f};

  const u32* f0g = flags + (size_t)(0 * 4 + g) * 1024;   // 128 flags * 8 u32 stride
  const u32* f1g = flags + (size_t)(1 * 4 + g) * 1024;
  u32* myflag = flags + ((size_t)(layer * 4 + g) * 128 + (size_t)lcu) * 8;

  // wave-level poll: all 128 chunk flags of this (layer,group) >= target
  auto poll2 = [&](const u32* base, u32 target) {
    const u32* p1 = base + (u32)lane * 8u;
    const u32* p2 = base + (u32)(lane + 64) * 8u;
    for (;;) {
      u32 v1, v2;
      asm volatile("global_load_dword %0, %2, off sc0 sc1\n\t"
                   "global_load_dword %1, %3, off sc0 sc1\n\t"
                   "s_waitcnt vmcnt(0)"
                   : "=v"(v1), "=v"(v2) : "v"(p1), "v"(p2) : "memory");
      if (__all((int)((v1 >= target) & (v2 >= target)))) break;
      __builtin_amdgcn_s_sleep(1);
    }
  };

  f32x4 z4 = {0.f, 0.f, 0.f, 0.f};
  f32x4 acc0, acc1;    // tile0: cols 0-15 (i,f); tile1: cols 16-31 (g,o)

  auto mfma2 = [&](short8 hb8, int k0) {
    const u32 kb = ((u32)(k0 + lq * 8) * 2u) ^ swz;
    short8 a0 = *(const short8*)(wrow0 + kb);
    short8 a1 = *(const short8*)(wrow1 + kb);
    acc0 = __builtin_amdgcn_mfma_f32_16x16x32_bf16(a0, hb8, acc0, 0, 0, 0);
    acc1 = __builtin_amdgcn_mfma_f32_16x16x32_bf16(a1, hb8, acc1, 0, 0, 0);
  };

  // cell update (wave-local) + publish: 8B store -> own drain -> flag
  auto cell_publish = [&](int t, u16* hist) {
    float pf[4], po[4];
    #pragma unroll
    for (int r = 0; r < 4; ++r) {
      pf[r] = __shfl_xor(acc0[r], 32);   // partner's i|f  -> f for lq<2
      po[r] = __shfl_xor(acc1[r], 32);   // partner's g|o  -> o for lq<2
    }
    if (lq < 2) {
      u16 hb16[4];
      #pragma unroll
      for (int r = 0; r < 4; ++r) {
        float gi = acc0[r] + bi[r];
        float gf = pf[r]   + bf_[r];
        float gg = acc1[r] + bg[r];
        float go = po[r]   + bo[r];
        float ii = 1.0f / (1.0f + __expf(-gi));
        float ff = 1.0f / (1.0f + __expf(-gf));
        float gt = 1.0f - 2.0f / (__expf(2.0f * gg) + 1.0f);
        float oo = 1.0f / (1.0f + __expf(-go));
        cs[r] = ff * cs[r] + ii * gt;
        hb16[r] = f2bf(oo * (1.0f - 2.0f / (__expf(2.0f * cs[r]) + 1.0f)));
      }
      u32x2 pk;
      pk.x = (u32)hb16[0] | ((u32)hb16[1] << 16);
      pk.y = (u32)hb16[2] | ((u32)hb16[3] << 16);
      // h[t+1][g][lcu][b=lr][u=4*lq..+4]
      u16* dst = hist + (size_t)(t + 1) * 65536 + (size_t)g * 16384
                 + (size_t)lcu * 128 + (size_t)lr * 8 + 4 * lq;
      asm volatile("global_store_dwordx2 %0, %1, off sc0 sc1" :: "v"(dst), "v"(pk));
    }
    asm volatile("s_waitcnt vmcnt(0)" ::: "memory");   // own stores ack'd at IC
    if (lane == 0)
      asm volatile("global_store_dword %0, %1, off sc0 sc1"
                   :: "v"(myflag), "v"((u32)(t + 1)));
  };

  if (!layer) {
    // ================= layer 0: K = [x(512) | h0prev(1024)] =================
    for (int t = 0; t < 512; ++t) {
      acc0 = z4; acc1 = z4;
      // x part first (no dependency): plain cached loads
      const u16* xp = xb + (size_t)t * 32768 + (size_t)(g * 16 + lr) * 512 + lq * 8;
      short8 X[16];
      #pragma unroll
      for (int j = 0; j < 16; ++j) X[j] = *(const short8*)(xp + j * 32);
      #pragma unroll
      for (int j = 0; j < 16; ++j) mfma2(X[j], j * 32);
      if (t > 0) {
        poll2(f0g, (u32)t);
        const u16* hp = h0h + (size_t)t * 65536 + (size_t)g * 16384 + (size_t)lr * 8;
        short8 H[32];
        #pragma unroll
        for (int j = 0; j < 32; ++j)
          H[j] = *(const short8*)(hp + (size_t)(j * 4 + lq) * 128);
        #pragma unroll
        for (int j = 0; j < 32; ++j) mfma2(H[j], 512 + j * 32);
      }
      cell_publish(t, h0h);
    }
  } else {
    // ============== layer 1: K = [h0cur(1024) | h1prev(1024)] ==============
    for (int t = 0; t < 512; ++t) {
      acc0 = z4; acc1 = z4;
      if (t > 0) {
        poll2(f1g, (u32)t);     // own-layer recurrence (usually long ready)
        const u16* hp1 = h1h + (size_t)t * 65536 + (size_t)g * 16384 + (size_t)lr * 8;
        short8 H1[32];
        #pragma unroll
        for (int j = 0; j < 32; ++j)
          H1[j] = *(const short8*)(hp1 + (size_t)(j * 4 + lq) * 128);
        #pragma unroll
        for (int j = 0; j < 32; ++j) mfma2(H1[j], 1024 + j * 32);
      }
      poll2(f0g, (u32)(t + 1));  // fresh dependency: h0[t]
      const u16* hp0 = h0h + (size_t)(t + 1) * 65536 + (size_t)g * 16384 + (size_t)lr * 8;
      short8 H0[32];
      #pragma unroll
      for (int j = 0; j < 32; ++j)
        H0[j] = *(const short8*)(hp0 + (size_t)(j * 4 + lq) * 128);
      #pragma unroll
      for (int j = 0; j < 32; ++j) mfma2(H0[j], j * 32);
      cell_publish(t, h1h);
    }
  }

  // ---- FC + softmax epilogue: block 0, wave 0 (reads h1[511] = slot 512) ----
  if (cu == 0 && g == 0) {
    #pragma unroll
    for (int j = 0; j < 8; ++j) {   // all 512 layer-1 flags >= 512
      const u32* p = flags + (size_t)(512 + j * 64 + lane) * 8;
      for (;;) {
        u32 v;
        asm volatile("global_load_dword %0, %1, off sc0 sc1\n\ts_waitcnt vmcnt(0)"
                     : "=v"(v) : "v"(p) : "memory");
        if (v >= 512u) break;
        __builtin_amdgcn_s_sleep(1);
      }
    }
    const int b = lane;                       // one batch per lane
    const u16* hb = h1h + (size_t)512 * 65536 + (size_t)(b >> 4) * 16384
                    + (size_t)(b & 15) * 8;
    float s0 = fc_b[0], s1 = fc_b[1];
    for (int c = 0; c < 128; ++c) {
      short8 hv8 = *(const short8*)(hb + (size_t)c * 128);
      #pragma unroll
      for (int e = 0; e < 8; ++e) {
        float hv = bf2f((u16)hv8[e]);
        s0 += hv * fc_w[c * 8 + e];
        s1 += hv * fc_w[1024 + c * 8 + e];
      }
    }
    float mx = fmaxf(s0, s1);
    float e0 = __expf(s0 - mx), e1 = __expf(s1 - mx);
    float inv = 1.0f / (e0 + e1);
    out[b * 2]     = e0 * inv;
    out[b * 2 + 1] = e1 * inv;
  }
}

extern "C" void kernel_launch(void* const* d_in, const int* in_sizes, int n_in,
                              void* d_out, int out_size, void* d_ws, size_t ws_size,
                              hipStream_t stream) {
  const float* x    = (const float*)d_in[0];
  const float* wih0 = (const float*)d_in[1];
  const float* whh0 = (const float*)d_in[2];
  const float* bih0 = (const float*)d_in[3];
  const float* bhh0 = (const float*)d_in[4];
  const float* wih1 = (const float*)d_in[5];
  const float* whh1 = (const float*)d_in[6];
  const float* bih1 = (const float*)d_in[7];
  const float* bhh1 = (const float*)d_in[8];
  const float* fcw  = (const float*)d_in[9];
  const float* fcb  = (const float*)d_in[10];
  float* out = (float*)d_out;
  char* ws = (char*)d_ws;

  u16* xb    = (u16*)(ws + XB_OFF);
  u16* h0h   = (u16*)(ws + H0_OFF);
  u16* h1h   = (u16*)(ws + H1_OFF);
  u32* flags = (u32*)(ws + FL_OFF);

  (void)hipFuncSetAttribute((const void*)lstm_persist,
      hipFuncAttributeMaxDynamicSharedMemorySize, LDS_TOTAL);

  hipMemsetAsync(ws + FL_OFF, 0, FLAGS_LEN, stream);   // zero step flags
  prep_x<<<8192, 256, 0, stream>>>(x, xb);
  lstm_persist<<<256, 256, LDS_TOTAL, stream>>>(
      (const u16*)xb, wih0, whh0, bih0, bhh0, wih1, whh1, bih1, bhh1,
      h0h, h1h, flags, fcw, fcb, out);
}